// Round 3
// baseline (4091.878 us; speedup 1.0000x reference)
//
#include <hip/hip_runtime.h>
#include <hip/hip_bf16.h>
#include <cstdio>
#include <cmath>

// SE2 multi self-attention forward.
// R2: softmax is saturated (one-hot argmax per column) => score path must be
// fp32 (Q,K,gg). V/P/ctx may be bf16 (linear error propagation only).
// Raw scores never stored: pass1 = column max (atomicMax on uint bits),
// pass2 = exp(s-M) -> bf16 P + column sums; 1/colsum folded into ctx.
//
// Shapes: B=4, MAXM=4, DIM=512, N=1024, NH=8, QD=64, D=512.
// pos_enc separability: exp(i*k*(M-N)*w0) = w^{kM}*conj(w^{kN}) =>
// pos[b,h,i,j] = sum_k gg[b,h,k,i]*conj(w^{kj}),
// gg = soft*(sum_q Q*enc)*w^{ki}.  'bhNM' + 'bhMN' adds positionally.

constexpr int Bb = 4;     // batch
constexpr int Mm = 4;     // MAXM harmonics
constexpr int Cd = 512;   // DIM
constexpr int Np = 1024;  // N
constexpr int Nh = 8;     // heads
constexpr int Qd = 64;    // head dim
constexpr float W0 = (float)(2.0 * 3.14159265358979323846 / 1024.0);

typedef __hip_bfloat16 bf16;
__device__ __forceinline__ float b2f(bf16 v) { return __bfloat162float(v); }
__device__ __forceinline__ bf16 f2b(float v) { return __float2bfloat16(v); }

// ---------- kernel 0: zero colmax/colsum ----
__global__ void k_zero(float* p, int n)
{
    int i = blockIdx.x * 256 + threadIdx.x;
    if (i < n) p[i] = 0.f;
}

// ---------- kernel 1: E = emb @ x (complex GEMM) -> Q,K fp32 (Q conj), V bf16
__global__ __launch_bounds__(256) void k_qkv(
    const float* __restrict__ xr, const float* __restrict__ xi,
    const float* __restrict__ er, const float* __restrict__ ei,
    float* __restrict__ Qr, float* __restrict__ Qi,
    float* __restrict__ Kr, float* __restrict__ Ki,
    bf16* __restrict__ Vr, bf16* __restrict__ Vi)
{
    // grid: (Np/64, Cd/64, 3*Bb*Mm)
    const int nt = blockIdx.x, dt = blockIdx.y;
    const int z = blockIdx.z;
    const int e = z / (Bb * Mm);
    const int bk = z % (Bb * Mm);
    const int k = bk % Mm;
    const int tx = threadIdx.x & 15, ty = threadIdx.x >> 4;
    const int n0 = nt * 64, d0 = dt * 64;

    const float* Ar_g = er + (size_t)(e * Mm + k) * Cd * Cd;  // [d][c]
    const float* Ai_g = ei + (size_t)(e * Mm + k) * Cd * Cd;
    const float* Br_g = xr + (size_t)bk * Cd * Np;            // [c][n]
    const float* Bi_g = xi + (size_t)bk * Cd * Np;

    __shared__ float As_r[64][17], As_i[64][17];
    __shared__ float Bs_r[16][64], Bs_i[16][64];

    float accr[4][4] = {}, acci[4][4] = {};

    for (int c0 = 0; c0 < Cd; c0 += 16) {
        const int t = threadIdx.x;
#pragma unroll
        for (int s = 0; s < 4; s++) {
            int idx = t + 256 * s;
            int i = idx >> 4, j = idx & 15;
            As_r[i][j] = Ar_g[(size_t)(d0 + i) * Cd + c0 + j];
            As_i[i][j] = Ai_g[(size_t)(d0 + i) * Cd + c0 + j];
        }
#pragma unroll
        for (int s = 0; s < 4; s++) {
            int idx = t + 256 * s;
            int i = idx >> 6, j = idx & 63;
            Bs_r[i][j] = Br_g[(size_t)(c0 + i) * Np + n0 + j];
            Bs_i[i][j] = Bi_g[(size_t)(c0 + i) * Np + n0 + j];
        }
        __syncthreads();
#pragma unroll
        for (int cc = 0; cc < 16; cc++) {
            float ar[4], ai[4], br[4], bi[4];
#pragma unroll
            for (int r = 0; r < 4; r++) { ar[r] = As_r[ty + r * 16][cc]; ai[r] = As_i[ty + r * 16][cc]; }
#pragma unroll
            for (int c = 0; c < 4; c++) { br[c] = Bs_r[cc][tx + c * 16]; bi[c] = Bs_i[cc][tx + c * 16]; }
#pragma unroll
            for (int r = 0; r < 4; r++)
#pragma unroll
                for (int c = 0; c < 4; c++) {
                    accr[r][c] = fmaf(ar[r], br[c], accr[r][c]);
                    accr[r][c] = fmaf(-ai[r], bi[c], accr[r][c]);
                    acci[r][c] = fmaf(ar[r], bi[c], acci[r][c]);
                    acci[r][c] = fmaf(ai[r], br[c], acci[r][c]);
                }
        }
        __syncthreads();
    }

    const size_t base = (size_t)bk * Cd * Np;
#pragma unroll
    for (int r = 0; r < 4; r++) {
        int d = d0 + ty + r * 16;
#pragma unroll
        for (int c = 0; c < 4; c++) {
            int n = n0 + tx + c * 16;
            size_t o = base + (size_t)d * Np + n;
            if (e == 0)      { Qr[o] = accr[r][c]; Qi[o] = -acci[r][c]; } // conj
            else if (e == 1) { Kr[o] = accr[r][c]; Ki[o] = acci[r][c]; }
            else             { Vr[o] = f2b(accr[r][c]); Vi[o] = f2b(acci[r][c]); }
        }
    }
}

// ---------- kernel 2: gg[b,h,k,i] = soft[k,h] * (sum_q Q*enc) * w^{k i} ----
__global__ __launch_bounds__(256) void k_gg(
    const float* __restrict__ Qr, const float* __restrict__ Qi,
    const float* __restrict__ encr, const float* __restrict__ enci,
    const float* __restrict__ softr, const float* __restrict__ softi,
    float* __restrict__ ggr, float* __restrict__ ggi)
{
    // grid: (Np/256, Bb*Nh*Mm); z = (b*Nh + h)*Mm + k
    const int i = blockIdx.x * 256 + threadIdx.x;
    const int z = blockIdx.y;
    const int k = z % Mm;
    const int h = (z / Mm) % Nh;
    const int b = z / (Mm * Nh);

    float gr = 0.f, gi = 0.f;
    const size_t qbase = ((size_t)(b * Mm + k) * Cd + h * Qd) * Np + i;
    const int ebase = (k * Nh + h) * Qd;
    for (int q = 0; q < Qd; q++) {
        float qr_ = Qr[qbase + (size_t)q * Np];
        float qi_ = Qi[qbase + (size_t)q * Np];
        float er_ = encr[ebase + q], ei_ = enci[ebase + q];
        gr = fmaf(qr_, er_, fmaf(-qi_, ei_, gr));
        gi = fmaf(qr_, ei_, fmaf(qi_, er_, gi));
    }
    const float sr = softr[k * Nh + h], si = softi[k * Nh + h];
    const float tr = gr * sr - gi * si;
    const float ti = gr * si + gi * sr;
    float sn, cs;
    sincosf(W0 * (float)(k * i), &sn, &cs);
    ggr[(size_t)z * Np + i] = tr * cs - ti * sn;
    ggi[(size_t)z * Np + i] = tr * sn + ti * cs;
}

// ---------- kernels 3/4: scores (fp32), PASS1 colmax / PASS2 exp+colsum ----
template <int PASS>
__global__ __launch_bounds__(256) void k_scores_t(
    const float* __restrict__ Kr, const float* __restrict__ Ki,
    const float* __restrict__ Qr, const float* __restrict__ Qi,
    const float* __restrict__ softr, const float* __restrict__ softi,
    const float* __restrict__ ggr, const float* __restrict__ ggi,
    unsigned* __restrict__ colmax, float* __restrict__ colsum,
    bf16* __restrict__ Pb)
{
    // grid: (Np/64 (j), Np/64 (i), Bb*Nh)
    const int jt = blockIdx.x, it = blockIdx.y, z = blockIdx.z;
    const int h = z % Nh, b = z / Nh;
    const int tx = threadIdx.x & 15, ty = threadIdx.x >> 4;
    const int i0 = it * 64, j0 = jt * 64;

    __shared__ float Ks_r[16][64], Ks_i[16][64], Qs_r[16][64], Qs_i[16][64];
    float accr[4][4] = {}, acci[4][4] = {};

    for (int kq0 = 0; kq0 < Mm * Qd; kq0 += 16) {
        const int t = threadIdx.x;
#pragma unroll
        for (int s = 0; s < 4; s++) {
            int idx = t + 256 * s;
            int r = idx >> 6, col = idx & 63;
            int kq = kq0 + r;
            int kk = kq >> 6, q = kq & 63;
            size_t ka = ((size_t)(b * Mm + kk) * Cd + h * Qd + q) * Np;
            float vr = Kr[ka + i0 + col], vi = Ki[ka + i0 + col];
            float sr = softr[kk * Nh + h], si = softi[kk * Nh + h];
            Ks_r[r][col] = vr * sr - vi * si;   // fold soft into K
            Ks_i[r][col] = vr * si + vi * sr;
            Qs_r[r][col] = Qr[ka + j0 + col];
            Qs_i[r][col] = Qi[ka + j0 + col];
        }
        __syncthreads();
#pragma unroll
        for (int cc = 0; cc < 16; cc++) {
            float kr_[4], ki_[4], qr_[4], qi_[4];
#pragma unroll
            for (int r = 0; r < 4; r++) { kr_[r] = Ks_r[cc][ty + r * 16]; ki_[r] = Ks_i[cc][ty + r * 16]; }
#pragma unroll
            for (int c = 0; c < 4; c++) { qr_[c] = Qs_r[cc][tx + c * 16]; qi_[c] = Qs_i[cc][tx + c * 16]; }
#pragma unroll
            for (int r = 0; r < 4; r++)
#pragma unroll
                for (int c = 0; c < 4; c++) {
                    accr[r][c] = fmaf(kr_[r], qr_[c], accr[r][c]);
                    accr[r][c] = fmaf(-ki_[r], qi_[c], accr[r][c]);
                    acci[r][c] = fmaf(kr_[r], qi_[c], acci[r][c]);
                    acci[r][c] = fmaf(ki_[r], qr_[c], acci[r][c]);
                }
        }
        __syncthreads();
    }

    // pos term + magnitude -> sc[r][c] = |A'|/8
    const size_t ggbase = (size_t)(b * Nh + h) * Mm * Np;
    float gvr[4][4], gvi[4][4];  // [k][r]
#pragma unroll
    for (int kk = 0; kk < 4; kk++)
#pragma unroll
        for (int r = 0; r < 4; r++) {
            int i = i0 + ty + r * 16;
            gvr[kk][r] = ggr[ggbase + (size_t)kk * Np + i];
            gvi[kk][r] = ggi[ggbase + (size_t)kk * Np + i];
        }
    float sc[4][4];
#pragma unroll
    for (int c = 0; c < 4; c++) {
        const int j = j0 + tx + c * 16;
        float cw[4], sw[4];
#pragma unroll
        for (int kk = 0; kk < 4; kk++)
            sincosf(W0 * (float)(kk * j), &sw[kk], &cw[kk]);
#pragma unroll
        for (int r = 0; r < 4; r++) {
            float pr = 0.f, pi = 0.f;
#pragma unroll
            for (int kk = 0; kk < 4; kk++) {
                pr += gvr[kk][r] * cw[kk] + gvi[kk][r] * sw[kk];  // gg*conj(w^kj)
                pi += gvi[kk][r] * cw[kk] - gvr[kk][r] * sw[kk];
            }
            float ar = accr[r][c] + pr, ai = acci[r][c] + pi;
            sc[r][c] = sqrtf(ar * ar + ai * ai) * 0.125f;
        }
    }

    __shared__ float red[16][64];
    if (PASS == 1) {
#pragma unroll
        for (int c = 0; c < 4; c++) {
            float m = fmaxf(fmaxf(sc[0][c], sc[1][c]), fmaxf(sc[2][c], sc[3][c]));
            red[ty][tx + c * 16] = m;
        }
        __syncthreads();
        if (threadIdx.x < 64) {
            int col = threadIdx.x;
            float m = red[0][col];
#pragma unroll
            for (int y = 1; y < 16; y++) m = fmaxf(m, red[y][col]);
            atomicMax(colmax + (size_t)z * Np + j0 + col, __float_as_uint(m));
        }
    } else {
        float M[4];
#pragma unroll
        for (int c = 0; c < 4; c++)
            M[c] = __uint_as_float(colmax[(size_t)z * Np + j0 + tx + c * 16]);
#pragma unroll
        for (int c = 0; c < 4; c++) {
            const int j = j0 + tx + c * 16;
            float s0 = 0.f;
#pragma unroll
            for (int r = 0; r < 4; r++) {
                const int i = i0 + ty + r * 16;
                float e = __expf(sc[r][c] - M[c]);
                Pb[((size_t)z * Np + i) * Np + j] = f2b(e);
                s0 += e;
            }
            red[ty][tx + c * 16] = s0;
        }
        __syncthreads();
        if (threadIdx.x < 64) {
            int col = threadIdx.x;
            float s0 = 0.f;
#pragma unroll
            for (int y = 0; y < 16; y++) s0 += red[y][col];
            atomicAdd(colsum + (size_t)z * Np + j0 + col, s0);
        }
    }
}

// ---------- kernel 5: ctx = (V @ P) / colsum, fp32 into Q's buffers ----
__global__ __launch_bounds__(256) void k_ctx(
    const bf16* __restrict__ Vr, const bf16* __restrict__ Vi,
    const bf16* __restrict__ Pb, const float* __restrict__ colsum,
    float* __restrict__ Cr, float* __restrict__ Ci)
{
    // grid: (Np/64 (M), Mm (k), Bb*Nh)
    const int mt = blockIdx.x, kk = blockIdx.y, z = blockIdx.z;
    const int h = z % Nh, b = z / Nh;
    const int tx = threadIdx.x & 15, ty = threadIdx.x >> 4;
    const int m0 = mt * 64;
    const size_t vbase = ((size_t)(b * Mm + kk) * Cd + h * Qd) * Np;
    const size_t pbase = (size_t)(b * Nh + h) * Np * Np;

    __shared__ float Vs_r[64][17], Vs_i[64][17], Ps[16][64];
    float accr[4][4] = {}, acci[4][4] = {};

    for (int n0 = 0; n0 < Np; n0 += 16) {
        const int t = threadIdx.x;
#pragma unroll
        for (int s = 0; s < 4; s++) {
            int idx = t + 256 * s;
            int q = idx >> 4, nn = idx & 15;
            Vs_r[q][nn] = b2f(Vr[vbase + (size_t)q * Np + n0 + nn]);
            Vs_i[q][nn] = b2f(Vi[vbase + (size_t)q * Np + n0 + nn]);
        }
#pragma unroll
        for (int s = 0; s < 4; s++) {
            int idx = t + 256 * s;
            int nn = idx >> 6, m = idx & 63;
            Ps[nn][m] = b2f(Pb[pbase + (size_t)(n0 + nn) * Np + m0 + m]);
        }
        __syncthreads();
#pragma unroll
        for (int cc = 0; cc < 16; cc++) {
            float vr_[4], vi_[4], p_[4];
#pragma unroll
            for (int r = 0; r < 4; r++) { vr_[r] = Vs_r[ty + r * 16][cc]; vi_[r] = Vs_i[ty + r * 16][cc]; }
#pragma unroll
            for (int c = 0; c < 4; c++) { p_[c] = Ps[cc][tx + c * 16]; }
#pragma unroll
            for (int r = 0; r < 4; r++)
#pragma unroll
                for (int c = 0; c < 4; c++) {
                    accr[r][c] = fmaf(vr_[r], p_[c], accr[r][c]);
                    acci[r][c] = fmaf(vi_[r], p_[c], acci[r][c]);
                }
        }
        __syncthreads();
    }
#pragma unroll
    for (int c = 0; c < 4; c++) {
        int m = m0 + tx + c * 16;
        float inv = 1.0f / colsum[(size_t)z * Np + m];
#pragma unroll
        for (int r = 0; r < 4; r++) {
            int q = ty + r * 16;
            size_t o = vbase + (size_t)q * Np + m;
            Cr[o] = accr[r][c] * inv;
            Ci[o] = acci[r][c] * inv;
        }
    }
}

// ---------- kernel 6: res = Re(out @ ctx), fp32 output ----
__global__ __launch_bounds__(256) void k_out(
    const float* __restrict__ Or, const float* __restrict__ Oi,
    const float* __restrict__ Cr, const float* __restrict__ Ci,
    float* __restrict__ res)
{
    // grid: (Np/64, Cd/64, Bb*Mm)
    const int nt = blockIdx.x, dt = blockIdx.y, bk = blockIdx.z;
    const int k = bk % Mm;
    const int tx = threadIdx.x & 15, ty = threadIdx.x >> 4;
    const int n0 = nt * 64, d0 = dt * 64;

    const float* Ar_g = Or + (size_t)k * Cd * Cd;      // out[k][d][c]
    const float* Ai_g = Oi + (size_t)k * Cd * Cd;
    const float* Br_g = Cr + (size_t)bk * Cd * Np;     // ctx[b,k][c][n]
    const float* Bi_g = Ci + (size_t)bk * Cd * Np;

    __shared__ float As_r[64][17], As_i[64][17];
    __shared__ float Bs_r[16][64], Bs_i[16][64];
    float accr[4][4] = {};

    for (int c0 = 0; c0 < Cd; c0 += 16) {
        const int t = threadIdx.x;
#pragma unroll
        for (int s = 0; s < 4; s++) {
            int idx = t + 256 * s;
            int i = idx >> 4, j = idx & 15;
            As_r[i][j] = Ar_g[(size_t)(d0 + i) * Cd + c0 + j];
            As_i[i][j] = Ai_g[(size_t)(d0 + i) * Cd + c0 + j];
        }
#pragma unroll
        for (int s = 0; s < 4; s++) {
            int idx = t + 256 * s;
            int i = idx >> 6, j = idx & 63;
            Bs_r[i][j] = Br_g[(size_t)(c0 + i) * Np + n0 + j];
            Bs_i[i][j] = Bi_g[(size_t)(c0 + i) * Np + n0 + j];
        }
        __syncthreads();
#pragma unroll
        for (int cc = 0; cc < 16; cc++) {
            float ar[4], ai[4], br[4], bi[4];
#pragma unroll
            for (int r = 0; r < 4; r++) { ar[r] = As_r[ty + r * 16][cc]; ai[r] = As_i[ty + r * 16][cc]; }
#pragma unroll
            for (int c = 0; c < 4; c++) { br[c] = Bs_r[cc][tx + c * 16]; bi[c] = Bs_i[cc][tx + c * 16]; }
#pragma unroll
            for (int r = 0; r < 4; r++)
#pragma unroll
                for (int c = 0; c < 4; c++) {
                    // real part only: Ar*Br - Ai*Bi
                    accr[r][c] = fmaf(ar[r], br[c], accr[r][c]);
                    accr[r][c] = fmaf(-ai[r], bi[c], accr[r][c]);
                }
        }
        __syncthreads();
    }

    const size_t base = (size_t)bk * Cd * Np;
#pragma unroll
    for (int r = 0; r < 4; r++) {
        int d = d0 + ty + r * 16;
#pragma unroll
        for (int c = 0; c < 4; c++) {
            int n = n0 + tx + c * 16;
            res[base + (size_t)d * Np + n] = accr[r][c];
        }
    }
}

extern "C" void kernel_launch(void* const* d_in, const int* in_sizes, int n_in,
                              void* d_out, int out_size, void* d_ws, size_t ws_size,
                              hipStream_t stream)
{
    const float* xr    = (const float*)d_in[0];
    const float* xi    = (const float*)d_in[1];
    const float* embr  = (const float*)d_in[2];
    const float* embi  = (const float*)d_in[3];
    const float* encr  = (const float*)d_in[4];
    const float* enci  = (const float*)d_in[5];
    const float* softr = (const float*)d_in[6];
    const float* softi = (const float*)d_in[7];
    const float* outr  = (const float*)d_in[8];
    const float* outi  = (const float*)d_in[9];
    float* res = (float*)d_out;
    char* ws   = (char*)d_ws;

    const size_t S1 = (size_t)Bb * Mm * Cd * Np;   // 8388608 elements
    const size_t S2 = (size_t)Bb * Nh * Np * Np;   // 33554432
    const size_t S3 = (size_t)Bb * Nh * Mm * Np;   // 131072
    const size_t NC = (size_t)Bb * Nh * Np;        // 32768 columns

    size_t off = 0;
    float* Qr = (float*)(ws + off); off += S1 * 4;
    float* Qi = (float*)(ws + off); off += S1 * 4;
    float* Kr = (float*)(ws + off); off += S1 * 4;
    float* Ki = (float*)(ws + off); off += S1 * 4;
    bf16*  Vr = (bf16*)(ws + off);  off += S1 * 2;
    bf16*  Vi = (bf16*)(ws + off);  off += S1 * 2;
    bf16*  Pb = (bf16*)(ws + off);  off += S2 * 2;
    float* ggr = (float*)(ws + off); off += S3 * 4;
    float* ggi = (float*)(ws + off); off += S3 * 4;
    float* colmax = (float*)(ws + off); off += NC * 4;
    float* colsum = (float*)(ws + off); off += NC * 4;

    fprintf(stderr, "[se2attn] ws_size=%zu need=%zu out_size=%d\n",
            ws_size, off, out_size);
    if (ws_size < off) {
        fprintf(stderr, "[se2attn] WORKSPACE TOO SMALL - aborting launch\n");
        return;
    }

    k_zero<<<dim3((2 * (int)NC + 255) / 256), 256, 0, stream>>>(colmax, 2 * (int)NC);
    k_qkv<<<dim3(Np / 64, Cd / 64, 3 * Bb * Mm), 256, 0, stream>>>(
        xr, xi, embr, embi, Qr, Qi, Kr, Ki, Vr, Vi);
    k_gg<<<dim3(Np / 256, Bb * Nh * Mm), 256, 0, stream>>>(
        Qr, Qi, encr, enci, softr, softi, ggr, ggi);
    k_scores_t<1><<<dim3(Np / 64, Np / 64, Bb * Nh), 256, 0, stream>>>(
        Kr, Ki, Qr, Qi, softr, softi, ggr, ggi,
        (unsigned*)colmax, colsum, Pb);
    k_scores_t<2><<<dim3(Np / 64, Np / 64, Bb * Nh), 256, 0, stream>>>(
        Kr, Ki, Qr, Qi, softr, softi, ggr, ggi,
        (unsigned*)colmax, colsum, Pb);
    k_ctx<<<dim3(Np / 64, Mm, Bb * Nh), 256, 0, stream>>>(
        Vr, Vi, Pb, colsum, Qr, Qi);   // ctx fp32 overwrites Q (dead)
    k_out<<<dim3(Np / 64, Cd / 64, Bb * Mm), 256, 0, stream>>>(
        outr, outi, Qr, Qi, res);
}

// Round 5
// 1919.663 us; speedup vs baseline: 2.1316x; 2.1316x over previous
//
#include <hip/hip_runtime.h>
#include <cstdio>
#include <cmath>

// SE2 multi self-attention forward — R5: full MFMA (16x16x32 f16) pipeline.
// (R4 + fix: no aggregate-init of LDS-derived pointer arrays in k_qkv_v.)
// Score path in fp16 hi/lo split (~fp32 quality, argmax-safe); V/P/ctx fp16.
// One score pass -> S fp32 transposed [z][j][i]; row reduce -> exp in ctx.
// MFMA layouts (gfx950, verified): A[m=lane&15][k=(lane>>4)*8+j],
// B[k=(lane>>4)*8+j][n=lane&15], C/D col=lane&15,row=(lane>>4)*4+reg.

typedef _Float16 h16;
typedef h16 h8 __attribute__((ext_vector_type(8)));
typedef h16 h4 __attribute__((ext_vector_type(4)));
typedef float f4 __attribute__((ext_vector_type(4)));

#define MFMA16(A, B, C) __builtin_amdgcn_mfma_f32_16x16x32_f16(A, B, C, 0, 0, 0)

constexpr int Bb = 4, Mm = 4, Cd = 512, Np = 1024, Nh = 8, Qd = 64;
constexpr float W0 = (float)(2.0 * 3.14159265358979323846 / 1024.0);

// workspace offsets (bytes)
constexpr size_t PL   = 16777216;        // one fp16 plane: 16*512*1024 halves
constexpr size_t QHR = 0, QLR = PL, QHI = 2*PL, QLI = 3*PL;
constexpr size_t KHR = 4*PL, KLR = 5*PL, KHI = 6*PL, KLI = 7*PL;
constexpr size_t SOFF = 8*PL;            // S fp32: 134217728 B
constexpr size_t XTHR = SOFF, XTLR = SOFF+PL, XTHI = SOFF+2*PL, XTLI = SOFF+3*PL;
constexpr size_t EHR = SOFF+4*PL, ELR = EHR+4194304, EHI = EHR+8388608, ELI = EHR+12582912;
constexpr size_t X2HR = KHR, X2HI = KHR+PL;
constexpr size_t E2HR = KHR+2*PL, E2HI = E2HR+2097152;
constexpr size_t VRO = 0, VIO = PL, CTR = 2*PL, CTI = 3*PL;
// d_out scratch offsets (floats)
constexpr size_t GG_R = 0, GG_I = 131072, WT_C = 262144, WT_S = 266240,
                 CMAX = 270336, CSUM = 303104;

__device__ __forceinline__ unsigned short h2u(h16 h) { return __builtin_bit_cast(unsigned short, h); }
__device__ __forceinline__ void fsplit(float v, h16& h, h16& l) {
    h = (h16)v; l = (h16)(v - (float)h);
}

// ---------------- prep: x -> transposed fp16 planes [bk][n][c] -------------
template <int HIONLY>
__global__ __launch_bounds__(256) void k_prep_x(
    const float* __restrict__ xr, const float* __restrict__ xi,
    h16* __restrict__ phr, h16* __restrict__ plr,
    h16* __restrict__ phi, h16* __restrict__ pli)
{
    __shared__ float T[64][68];
    const int bk = blockIdx.z, N0 = blockIdx.x * 64, C0 = blockIdx.y * 64;
    const int t = threadIdx.x;
    for (int comp = 0; comp < 2; ++comp) {
        const float* src = (comp ? xi : xr) + (size_t)bk * Cd * Np;
        {   // stage x[c][n] tile
            int cc = t >> 2, ch = (t & 3) * 16;
            const float4* s4 = (const float4*)(src + (size_t)(C0 + cc) * Np + N0 + ch);
            float4 a = s4[0], b = s4[1], c = s4[2], d = s4[3];
            float4* dst = (float4*)&T[cc][ch];
            dst[0] = a; dst[1] = b; dst[2] = c; dst[3] = d;
        }
        __syncthreads();
        {   // drain transposed [n][c], split to fp16 hi/lo
            int n = t >> 2, ch = (t & 3) * 16;
            h8 hv0, hv1, lv0, lv1;
#pragma unroll
            for (int jj = 0; jj < 16; ++jj) {
                h16 h, l; fsplit(T[ch + jj][n], h, l);
                if (jj < 8) { hv0[jj] = h; lv0[jj] = l; }
                else        { hv1[jj - 8] = h; lv1[jj - 8] = l; }
            }
            size_t off = (size_t)bk * Np * Cd + (size_t)(N0 + n) * Cd + C0 + ch;
            h16* dh = (comp ? phi : phr) + off;
            *(h8*)dh = hv0; *(h8*)(dh + 8) = hv1;
            if (!HIONLY) {
                h16* dl = (comp ? pli : plr) + off;
                *(h8*)dl = lv0; *(h8*)(dl + 8) = lv1;
            }
        }
        __syncthreads();
    }
}

// ---------------- prep: emb -> fp16 planes (elementwise) -------------------
template <int HIONLY>
__global__ __launch_bounds__(256) void k_prep_emb(
    const float* __restrict__ er, const float* __restrict__ ei, size_t srcbase,
    h16* __restrict__ phr, h16* __restrict__ plr,
    h16* __restrict__ phi, h16* __restrict__ pli)
{
    size_t idx = ((size_t)blockIdx.x * 256 + threadIdx.x) * 4;
    float4 vr = *(const float4*)(er + srcbase + idx);
    float4 vi = *(const float4*)(ei + srcbase + idx);
    h4 hr, lr, hi, li;
    float ar[4] = {vr.x, vr.y, vr.z, vr.w}, ai[4] = {vi.x, vi.y, vi.z, vi.w};
#pragma unroll
    for (int j = 0; j < 4; ++j) {
        h16 h, l; fsplit(ar[j], h, l); hr[j] = h; lr[j] = l;
        fsplit(ai[j], h, l); hi[j] = h; li[j] = l;
    }
    *(h4*)(phr + idx) = hr; *(h4*)(phi + idx) = hi;
    if (!HIONLY) { *(h4*)(plr + idx) = lr; *(h4*)(pli + idx) = li; }
}

// ---------------- wtab: cos/sin(W0*k*j) ------------------------------------
__global__ __launch_bounds__(256) void k_wtab(float* __restrict__ wtc, float* __restrict__ wts)
{
    int idx = blockIdx.x * 256 + threadIdx.x;  // 4096
    int kk = idx >> 10, j = idx & 1023;
    float sn, cs; sincosf(W0 * (float)(kk * j), &sn, &cs);
    wtc[idx] = cs; wts[idx] = sn;
}

// ---------------- k_qkv01: E = emb @ x, split-fp16 MFMA, Q/K out -----------
__global__ __launch_bounds__(256) void k_qkv01(
    const h16* __restrict__ ehr, const h16* __restrict__ elr,
    const h16* __restrict__ ehi, const h16* __restrict__ eli,
    const h16* __restrict__ xthr, const h16* __restrict__ xtlr,
    const h16* __restrict__ xthi, const h16* __restrict__ xtli,
    h16* __restrict__ qhr, h16* __restrict__ qlr, h16* __restrict__ qhi, h16* __restrict__ qli,
    h16* __restrict__ khr, h16* __restrict__ klr, h16* __restrict__ khi, h16* __restrict__ kli,
    const float* __restrict__ softr, const float* __restrict__ softi)
{
    __shared__ __align__(16) char smem[61440];
    h16* As[4]; h16* Bs[4];
#pragma unroll
    for (int p = 0; p < 4; ++p) { As[p] = (h16*)smem + p * 5120; Bs[p] = (h16*)smem + 20480 + p * 2560; }
    uint* T = (uint*)smem;  // 64 x 132 overlay (epilogue)

    const int t = threadIdx.x;
    const int z = blockIdx.z, e = z >> 4, bk = z & 15, b = bk >> 2, kk = bk & 3;
    const int N0 = blockIdx.x * 64, D0 = blockIdx.y * 128;
    const int wave = t >> 6, lane = t & 63, quad = lane >> 4, l16 = lane & 15;
    const int wy = wave >> 1, wx = wave & 1;

    const h16* APl[4] = { ehr + (size_t)(e * 4 + kk) * 262144, elr + (size_t)(e * 4 + kk) * 262144,
                          ehi + (size_t)(e * 4 + kk) * 262144, eli + (size_t)(e * 4 + kk) * 262144 };
    const h16* BPl[4] = { xthr + (size_t)bk * 524288, xtlr + (size_t)bk * 524288,
                          xthi + (size_t)bk * 524288, xtli + (size_t)bk * 524288 };

    f4 zero = {0.f, 0.f, 0.f, 0.f};
    f4 Arr[4][2], Aii[4][2], Ari[4][2], Air[4][2];
#pragma unroll
    for (int r = 0; r < 4; ++r)
#pragma unroll
        for (int c = 0; c < 2; ++c) { Arr[r][c] = zero; Aii[r][c] = zero; Ari[r][c] = zero; Air[r][c] = zero; }

    for (int c0 = 0; c0 < Cd; c0 += 32) {
#pragma unroll
        for (int s = 0; s < 6; ++s) {
            int seg = t + 256 * s;
            const h16* src; h16* dst;
            if (seg < 1024) {
                int p = seg >> 8, rem = seg & 255, row = rem >> 1, ch = rem & 1;
                src = APl[p] + (size_t)(D0 + row) * 512 + c0 + ch * 16;
                dst = As[p] + row * 40 + ch * 16;
            } else {
                int s2 = seg - 1024, p = s2 >> 7, rem = s2 & 127, row = rem >> 1, ch = rem & 1;
                src = BPl[p] + (size_t)(N0 + row) * 512 + c0 + ch * 16;
                dst = Bs[p] + row * 40 + ch * 16;
            }
            const uint4* s4 = (const uint4*)src; uint4 v0 = s4[0], v1 = s4[1];
            uint4* d4 = (uint4*)dst; d4[0] = v0; d4[1] = v1;
        }
        __syncthreads();
        h8 bhr[2], blr[2], bhi[2], bli[2];
#pragma unroll
        for (int cc = 0; cc < 2; ++cc) {
            int o = (wx * 32 + cc * 16 + l16) * 40 + quad * 8;
            bhr[cc] = *(const h8*)(Bs[0] + o); blr[cc] = *(const h8*)(Bs[1] + o);
            bhi[cc] = *(const h8*)(Bs[2] + o); bli[cc] = *(const h8*)(Bs[3] + o);
        }
#pragma unroll
        for (int rr = 0; rr < 4; ++rr) {
            int o = (wy * 64 + rr * 16 + l16) * 40 + quad * 8;
            h8 ahr = *(const h8*)(As[0] + o), alr = *(const h8*)(As[1] + o);
            h8 ahi = *(const h8*)(As[2] + o), ali = *(const h8*)(As[3] + o);
#pragma unroll
            for (int cc = 0; cc < 2; ++cc) {
                Arr[rr][cc] = MFMA16(ahr, bhr[cc], Arr[rr][cc]);
                Arr[rr][cc] = MFMA16(ahr, blr[cc], Arr[rr][cc]);
                Arr[rr][cc] = MFMA16(alr, bhr[cc], Arr[rr][cc]);
                Aii[rr][cc] = MFMA16(ahi, bhi[cc], Aii[rr][cc]);
                Aii[rr][cc] = MFMA16(ahi, bli[cc], Aii[rr][cc]);
                Aii[rr][cc] = MFMA16(ali, bhi[cc], Aii[rr][cc]);
                Ari[rr][cc] = MFMA16(ahr, bhi[cc], Ari[rr][cc]);
                Ari[rr][cc] = MFMA16(ahr, bli[cc], Ari[rr][cc]);
                Ari[rr][cc] = MFMA16(alr, bhi[cc], Ari[rr][cc]);
                Air[rr][cc] = MFMA16(ahi, bhr[cc], Air[rr][cc]);
                Air[rr][cc] = MFMA16(ahi, blr[cc], Air[rr][cc]);
                Air[rr][cc] = MFMA16(ali, bhr[cc], Air[rr][cc]);
            }
        }
        __syncthreads();
    }
    // combine + optional conj / soft-fold
    f4 ER[4][2], EI[4][2];
#pragma unroll
    for (int rr = 0; rr < 4; ++rr) {
        int h = (D0 + wy * 64 + rr * 16) >> 6;
        float sr = 0.f, si = 0.f;
        if (e == 1) { sr = softr[kk * 8 + h]; si = softi[kk * 8 + h]; }
#pragma unroll
        for (int cc = 0; cc < 2; ++cc) {
            f4 er = Arr[rr][cc] - Aii[rr][cc];
            f4 ei = Ari[rr][cc] + Air[rr][cc];
            if (e == 0) { ei = -ei; }                  // Q = conj(E0)
            else { f4 t1 = sr * er - si * ei; ei = sr * ei + si * er; er = t1; }  // K' = soft*K
            ER[rr][cc] = er; EI[rr][cc] = ei;
        }
    }
    const int h0 = D0 >> 6;
    for (int round = 0; round < 2; ++round) {
#pragma unroll
        for (int rr = 0; rr < 4; ++rr)
#pragma unroll
            for (int cc = 0; cc < 2; ++cc)
#pragma unroll
                for (int reg = 0; reg < 4; ++reg) {
                    int dl = wy * 64 + rr * 16 + quad * 4 + reg;
                    int nl = wx * 32 + cc * 16 + l16;
                    float v = round ? EI[rr][cc][reg] : ER[rr][cc][reg];
                    h16 hh, ll; fsplit(v, hh, ll);
                    T[nl * 132 + dl] = ((uint)h2u(hh) << 16) | (uint)h2u(ll);
                }
        __syncthreads();
        {
            int seg = t >> 1, sub = t & 1, n = seg & 63, hh2 = seg >> 6;
            int off = hh2 * 64 + sub * 32;
            uint tmp[32];
            uint4* Tp = (uint4*)&T[n * 132 + off];
#pragma unroll
            for (int w = 0; w < 8; ++w) ((uint4*)tmp)[w] = Tp[w];
            uint hiu[16], lou[16];
#pragma unroll
            for (int w = 0; w < 16; ++w) {
                uint a = tmp[2 * w], b2 = tmp[2 * w + 1];
                hiu[w] = (a >> 16) | (b2 & 0xffff0000u);
                lou[w] = (a & 0xffffu) | (b2 << 16);
            }
            int hg = h0 + hh2;
            size_t dsto = ((size_t)((b * 8 + hg) * 1024 + N0 + n)) * 256 + kk * 64 + sub * 32;
            h16* dh; h16* dl;
            if (round == 0) { dh = (e ? khr : qhr) + dsto; dl = (e ? klr : qlr) + dsto; }
            else            { dh = (e ? khi : qhi) + dsto; dl = (e ? kli : qli) + dsto; }
#pragma unroll
            for (int w = 0; w < 4; ++w) ((uint4*)dh)[w] = ((uint4*)hiu)[w];
#pragma unroll
            for (int w = 0; w < 4; ++w) ((uint4*)dl)[w] = ((uint4*)lou)[w];
        }
        __syncthreads();
    }
}

// ---------------- k_gg -----------------------------------------------------
__global__ __launch_bounds__(256) void k_gg(
    const h16* __restrict__ qhr, const h16* __restrict__ qlr,
    const h16* __restrict__ qhi, const h16* __restrict__ qli,
    const float* __restrict__ encr, const float* __restrict__ enci,
    const float* __restrict__ softr, const float* __restrict__ softi,
    float* __restrict__ ggr, float* __restrict__ ggi)
{
    const int i = blockIdx.x * 256 + threadIdx.x;
    const int z2 = blockIdx.y, kk = z2 & 3, z = z2 >> 2, h = z & 7;
    size_t base = ((size_t)z * 1024 + i) * 256 + kk * 64;
    float gr = 0.f, gi = 0.f;
    const int eb = (kk * 8 + h) * 64;
    for (int q = 0; q < 64; ++q) {
        float qr = (float)qhr[base + q] + (float)qlr[base + q];
        float qi = (float)qhi[base + q] + (float)qli[base + q];
        float er = encr[eb + q], ei = enci[eb + q];
        gr = fmaf(qr, er, fmaf(-qi, ei, gr));
        gi = fmaf(qr, ei, fmaf(qi, er, gi));
    }
    float sr = softr[kk * 8 + h], si = softi[kk * 8 + h];
    float tr = gr * sr - gi * si, ti = gr * si + gi * sr;
    float sn, cs; sincosf(W0 * (float)(kk * i), &sn, &cs);
    ggr[(size_t)z2 * 1024 + i] = tr * cs - ti * sn;
    ggi[(size_t)z2 * 1024 + i] = tr * sn + ti * cs;
}

// ---------------- k_scores: one pass, S fp32 transposed [z][j][i] ----------
__global__ __launch_bounds__(256) void k_scores(
    const h16* __restrict__ khr, const h16* __restrict__ klr,
    const h16* __restrict__ khi, const h16* __restrict__ kli,
    const h16* __restrict__ qhr, const h16* __restrict__ qlr,
    const h16* __restrict__ qhi, const h16* __restrict__ qli,
    const float* __restrict__ ggr, const float* __restrict__ ggi,
    const float* __restrict__ wtc, const float* __restrict__ wts,
    float* __restrict__ S)
{
    __shared__ __align__(16) char smem[40960];
    h16* Ks[4]; h16* Qs[4];
#pragma unroll
    for (int p = 0; p < 4; ++p) { Ks[p] = (h16*)smem + p * 2560; Qs[p] = (h16*)smem + (4 + p) * 2560; }
    float* T = (float*)smem;  // 64 x 68 overlay

    const int t = threadIdx.x, z = blockIdx.z;
    const int I0 = blockIdx.y * 64, J0 = blockIdx.x * 64;
    const int wave = t >> 6, lane = t & 63, quad = lane >> 4, l16 = lane & 15;
    const int wy = wave >> 1, wx = wave & 1;
    const h16* KPl[4] = { khr + (size_t)z * 262144, klr + (size_t)z * 262144,
                          khi + (size_t)z * 262144, kli + (size_t)z * 262144 };
    const h16* QPl[4] = { qhr + (size_t)z * 262144, qlr + (size_t)z * 262144,
                          qhi + (size_t)z * 262144, qli + (size_t)z * 262144 };

    f4 zero = {0.f, 0.f, 0.f, 0.f};
    f4 Arr[2][2], Aii[2][2], Ari[2][2], Air[2][2];
#pragma unroll
    for (int r = 0; r < 2; ++r)
#pragma unroll
        for (int c = 0; c < 2; ++c) { Arr[r][c] = zero; Aii[r][c] = zero; Ari[r][c] = zero; Air[r][c] = zero; }

    for (int kq0 = 0; kq0 < 256; kq0 += 32) {
#pragma unroll
        for (int s = 0; s < 4; ++s) {
            int seg = t + 256 * s;
            int half = seg >> 9, rem = seg & 511, p = rem >> 7, r2 = rem & 127, row = r2 >> 1, ch = r2 & 1;
            const h16* src = (half ? QPl[p] : KPl[p]) + (size_t)((half ? J0 : I0) + row) * 256 + kq0 + ch * 16;
            h16* dst = (half ? Qs[p] : Ks[p]) + row * 40 + ch * 16;
            const uint4* s4 = (const uint4*)src; uint4 v0 = s4[0], v1 = s4[1];
            uint4* d4 = (uint4*)dst; d4[0] = v0; d4[1] = v1;
        }
        __syncthreads();
        h8 bhr[2], blr[2], bhi[2], bli[2];
#pragma unroll
        for (int cc = 0; cc < 2; ++cc) {
            int o = (wx * 32 + cc * 16 + l16) * 40 + quad * 8;
            bhr[cc] = *(const h8*)(Qs[0] + o); blr[cc] = *(const h8*)(Qs[1] + o);
            bhi[cc] = *(const h8*)(Qs[2] + o); bli[cc] = *(const h8*)(Qs[3] + o);
        }
#pragma unroll
        for (int rr = 0; rr < 2; ++rr) {
            int o = (wy * 32 + rr * 16 + l16) * 40 + quad * 8;
            h8 ahr = *(const h8*)(Ks[0] + o), alr = *(const h8*)(Ks[1] + o);
            h8 ahi = *(const h8*)(Ks[2] + o), ali = *(const h8*)(Ks[3] + o);
#pragma unroll
            for (int cc = 0; cc < 2; ++cc) {
                Arr[rr][cc] = MFMA16(ahr, bhr[cc], Arr[rr][cc]);
                Arr[rr][cc] = MFMA16(ahr, blr[cc], Arr[rr][cc]);
                Arr[rr][cc] = MFMA16(alr, bhr[cc], Arr[rr][cc]);
                Aii[rr][cc] = MFMA16(ahi, bhi[cc], Aii[rr][cc]);
                Aii[rr][cc] = MFMA16(ahi, bli[cc], Aii[rr][cc]);
                Aii[rr][cc] = MFMA16(ali, bhi[cc], Aii[rr][cc]);
                Ari[rr][cc] = MFMA16(ahr, bhi[cc], Ari[rr][cc]);
                Ari[rr][cc] = MFMA16(ahr, bli[cc], Ari[rr][cc]);
                Ari[rr][cc] = MFMA16(alr, bhi[cc], Ari[rr][cc]);
                Air[rr][cc] = MFMA16(ahi, bhr[cc], Air[rr][cc]);
                Air[rr][cc] = MFMA16(ahi, blr[cc], Air[rr][cc]);
                Air[rr][cc] = MFMA16(ali, bhr[cc], Air[rr][cc]);
            }
        }
        __syncthreads();
    }
    // epilogue: + pos, |.|/8, transpose via LDS, write S[z][j][i]
#pragma unroll
    for (int cc = 0; cc < 2; ++cc) {
        int j = J0 + wx * 32 + cc * 16 + l16;
        float wc[4], wsn[4];
#pragma unroll
        for (int k = 0; k < 4; ++k) { wc[k] = wtc[k * 1024 + j]; wsn[k] = wts[k * 1024 + j]; }
#pragma unroll
        for (int rr = 0; rr < 2; ++rr)
#pragma unroll
            for (int reg = 0; reg < 4; ++reg) {
                int i = I0 + wy * 32 + rr * 16 + quad * 4 + reg;
                float Sr = Arr[rr][cc][reg] - Aii[rr][cc][reg];
                float Si = Ari[rr][cc][reg] + Air[rr][cc][reg];
                float pr = 0.f, pi = 0.f;
#pragma unroll
                for (int k = 0; k < 4; ++k) {
                    float gr = ggr[(size_t)(z * 4 + k) * 1024 + i];
                    float gi = ggi[(size_t)(z * 4 + k) * 1024 + i];
                    pr += gr * wc[k] + gi * wsn[k];
                    pi += gi * wc[k] - gr * wsn[k];
                }
                float ar = Sr + pr, ai = Si + pi;
                int jl = wx * 32 + cc * 16 + l16, il = wy * 32 + rr * 16 + quad * 4 + reg;
                T[jl * 68 + il] = sqrtf(ar * ar + ai * ai) * 0.125f;
            }
    }
    __syncthreads();
    {
        int j2 = t >> 2, ch = (t & 3) * 16;
        float4* Tp = (float4*)&T[j2 * 68 + ch];
        float4* dst = (float4*)(S + ((size_t)z * 1024 + J0 + j2) * 1024 + I0 + ch);
#pragma unroll
        for (int w = 0; w < 4; ++w) dst[w] = Tp[w];
    }
}

// ---------------- k_colred: per-row (column of A) max & expsum -------------
__global__ __launch_bounds__(256) void k_colred(
    const float* __restrict__ S, float* __restrict__ cmax, float* __restrict__ csum)
{
    __shared__ float sm[256];
    const int t = threadIdx.x;
    size_t row = blockIdx.x;
    float4 v = ((const float4*)(S + row * 1024))[t];
    float m = fmaxf(fmaxf(v.x, v.y), fmaxf(v.z, v.w));
    sm[t] = m; __syncthreads();
    for (int s = 128; s > 0; s >>= 1) { if (t < s) sm[t] = fmaxf(sm[t], sm[t + s]); __syncthreads(); }
    float M = sm[0]; __syncthreads();
    float e = __expf(v.x - M) + __expf(v.y - M) + __expf(v.z - M) + __expf(v.w - M);
    sm[t] = e; __syncthreads();
    for (int s = 128; s > 0; s >>= 1) { if (t < s) sm[t] += sm[t + s]; __syncthreads(); }
    if (t == 0) { cmax[row] = M; csum[row] = sm[0]; }
}

// ---------------- k_qkv_v: V = emb2 @ x (plain fp16 MFMA) ------------------
__global__ __launch_bounds__(256) void k_qkv_v(
    const h16* __restrict__ e2hr, const h16* __restrict__ e2hi,
    const h16* __restrict__ x2hr, const h16* __restrict__ x2hi,
    h16* __restrict__ vr, h16* __restrict__ vi)
{
    __shared__ __align__(16) h16 smem[15360];
    h16* A2[2]; h16* B2[2];
#pragma unroll
    for (int p = 0; p < 2; ++p) { A2[p] = smem + p * 5120; B2[p] = smem + 10240 + p * 2560; }
    const int t = threadIdx.x, bk = blockIdx.z, kk = bk & 3;
    const int N0 = blockIdx.x * 64, D0 = blockIdx.y * 128;
    const int wave = t >> 6, lane = t & 63, quad = lane >> 4, l16 = lane & 15;
    const int wy = wave >> 1, wx = wave & 1;
    const h16* APl[2] = { e2hr + (size_t)kk * 262144, e2hi + (size_t)kk * 262144 };
    const h16* BPl[2] = { x2hr + (size_t)bk * 524288, x2hi + (size_t)bk * 524288 };

    f4 zero = {0.f, 0.f, 0.f, 0.f};
    f4 Arr[4][2], Aii[4][2], Ari[4][2], Air[4][2];
#pragma unroll
    for (int r = 0; r < 4; ++r)
#pragma unroll
        for (int c = 0; c < 2; ++c) { Arr[r][c] = zero; Aii[r][c] = zero; Ari[r][c] = zero; Air[r][c] = zero; }

    for (int c0 = 0; c0 < Cd; c0 += 32) {
#pragma unroll
        for (int s = 0; s < 3; ++s) {
            int seg = t + 256 * s;
            const h16* src; h16* dst;
            if (seg < 512) {
                int p = seg >> 8, rem = seg & 255, row = rem >> 1, ch = rem & 1;
                src = APl[p] + (size_t)(D0 + row) * 512 + c0 + ch * 16;
                dst = A2[p] + row * 40 + ch * 16;
            } else {
                int s2 = seg - 512, p = s2 >> 7, rem = s2 & 127, row = rem >> 1, ch = rem & 1;
                src = BPl[p] + (size_t)(N0 + row) * 512 + c0 + ch * 16;
                dst = B2[p] + row * 40 + ch * 16;
            }
            const uint4* s4 = (const uint4*)src; uint4 v0 = s4[0], v1 = s4[1];
            uint4* d4 = (uint4*)dst; d4[0] = v0; d4[1] = v1;
        }
        __syncthreads();
        h8 bhr[2], bhi[2];
#pragma unroll
        for (int cc = 0; cc < 2; ++cc) {
            int o = (wx * 32 + cc * 16 + l16) * 40 + quad * 8;
            bhr[cc] = *(const h8*)(B2[0] + o); bhi[cc] = *(const h8*)(B2[1] + o);
        }
#pragma unroll
        for (int rr = 0; rr < 4; ++rr) {
            int o = (wy * 64 + rr * 16 + l16) * 40 + quad * 8;
            h8 ahr = *(const h8*)(A2[0] + o), ahi = *(const h8*)(A2[1] + o);
#pragma unroll
            for (int cc = 0; cc < 2; ++cc) {
                Arr[rr][cc] = MFMA16(ahr, bhr[cc], Arr[rr][cc]);
                Aii[rr][cc] = MFMA16(ahi, bhi[cc], Aii[rr][cc]);
                Ari[rr][cc] = MFMA16(ahr, bhi[cc], Ari[rr][cc]);
                Air[rr][cc] = MFMA16(ahi, bhr[cc], Air[rr][cc]);
            }
        }
        __syncthreads();
    }
#pragma unroll
    for (int rr = 0; rr < 4; ++rr)
#pragma unroll
        for (int cc = 0; cc < 2; ++cc)
#pragma unroll
            for (int reg = 0; reg < 4; ++reg) {
                int dl = D0 + wy * 64 + rr * 16 + quad * 4 + reg;
                int nl = N0 + wx * 32 + cc * 16 + l16;
                size_t o = (size_t)bk * 524288 + (size_t)dl * 1024 + nl;
                vr[o] = (h16)(Arr[rr][cc][reg] - Aii[rr][cc][reg]);
                vi[o] = (h16)(Ari[rr][cc][reg] + Air[rr][cc][reg]);
            }
}

// ---------------- k_ctx: ctx = V @ softmax(S), fp16, transposed out --------
__global__ __launch_bounds__(256) void k_ctx(
    const h16* __restrict__ vr, const h16* __restrict__ vi,
    const float* __restrict__ S, const float* __restrict__ cmax,
    const float* __restrict__ csum,
    h16* __restrict__ ctr, h16* __restrict__ cti)
{
    __shared__ __align__(16) h16 Vsr[2560], Vsi[2560], Ps[2560];
    __shared__ __align__(16) h16 T2[4608];  // 64 x 72
    const int t = threadIdx.x, z = blockIdx.z, kk = blockIdx.y, M0 = blockIdx.x * 64;
    const int b = z >> 3, h = z & 7;
    const int wave = t >> 6, lane = t & 63, quad = lane >> 4, l16 = lane & 15;
    const int wy = wave >> 1, wx = wave & 1;
    const size_t vbase = (size_t)(b * 4 + kk) * 524288 + (size_t)(h * 64) * 1024;
    const size_t sbase = ((size_t)z * 1024 + M0) * 1024;

    f4 zero = {0.f, 0.f, 0.f, 0.f};
    f4 accR[2][2], accI[2][2];
#pragma unroll
    for (int r = 0; r < 2; ++r)
#pragma unroll
        for (int c = 0; c < 2; ++c) { accR[r][c] = zero; accI[r][c] = zero; }

    for (int i0 = 0; i0 < 1024; i0 += 32) {
        if (t < 128) {
            int comp = t >> 6, q = t & 63;
            const h16* src = (comp ? vi : vr) + vbase + (size_t)q * 1024 + i0;
            h16* dst = (comp ? Vsi : Vsr) + q * 40;
            const uint4* s4 = (const uint4*)src;
#pragma unroll
            for (int w = 0; w < 4; ++w) ((uint4*)dst)[w] = s4[w];
        } else {
            int tt = t - 128, m = tt >> 1, ch = tt & 1;
            float M = cmax[(size_t)z * 1024 + M0 + m];
            const float4* sp = (const float4*)(S + sbase + (size_t)m * 1024 + i0 + ch * 16);
            h8 e0, e1;
#pragma unroll
            for (int w = 0; w < 4; ++w) {
                float4 v = sp[w];
                h16 a = (h16)__expf(v.x - M), b2 = (h16)__expf(v.y - M);
                h16 c = (h16)__expf(v.z - M), d = (h16)__expf(v.w - M);
                if (w < 2) { e0[w*4] = a; e0[w*4+1] = b2; e0[w*4+2] = c; e0[w*4+3] = d; }
                else { e1[(w-2)*4] = a; e1[(w-2)*4+1] = b2; e1[(w-2)*4+2] = c; e1[(w-2)*4+3] = d; }
            }
            h16* dst = Ps + m * 40 + ch * 16;
            *(h8*)dst = e0; *(h8*)(dst + 8) = e1;
        }
        __syncthreads();
        h8 bp[2];
#pragma unroll
        for (int cc = 0; cc < 2; ++cc)
            bp[cc] = *(const h8*)(Ps + (wx * 32 + cc * 16 + l16) * 40 + quad * 8);
#pragma unroll
        for (int rr = 0; rr < 2; ++rr) {
            int o = (wy * 32 + rr * 16 + l16) * 40 + quad * 8;
            h8 avr = *(const h8*)(Vsr + o), avi = *(const h8*)(Vsi + o);
#pragma unroll
            for (int cc = 0; cc < 2; ++cc) {
                accR[rr][cc] = MFMA16(avr, bp[cc], accR[rr][cc]);
                accI[rr][cc] = MFMA16(avi, bp[cc], accI[rr][cc]);
            }
        }
        __syncthreads();
    }
    for (int round = 0; round < 2; ++round) {
#pragma unroll
        for (int rr = 0; rr < 2; ++rr)
#pragma unroll
            for (int cc = 0; cc < 2; ++cc) {
                int ml = wx * 32 + cc * 16 + l16;
                float inv = 1.0f / csum[(size_t)z * 1024 + M0 + ml];
#pragma unroll
                for (int reg = 0; reg < 4; ++reg) {
                    int ql = wy * 32 + rr * 16 + quad * 4 + reg;
                    float v = (round ? accI[rr][cc][reg] : accR[rr][cc][reg]) * inv;
                    T2[ml * 72 + ql] = (h16)v;
                }
            }
        __syncthreads();
        {
            int m = t >> 2, ch = (t & 3) * 16;
            h8 v0 = *(const h8*)(T2 + m * 72 + ch), v1 = *(const h8*)(T2 + m * 72 + ch + 8);
            h16* dst = (round ? cti : ctr) + (size_t)(b * 4 + kk) * 524288 + (size_t)(M0 + m) * 512 + h * 64 + ch;
            *(h8*)dst = v0; *(h8*)(dst + 8) = v1;
        }
        __syncthreads();
    }
}

// ---------------- k_out: res = Re(out @ ctx), MFMA fp16 --------------------
__global__ __launch_bounds__(256) void k_out(
    const float* __restrict__ outr, const float* __restrict__ outi,
    const h16* __restrict__ ctr, const h16* __restrict__ cti,
    float* __restrict__ res)
{
    __shared__ __align__(16) h16 smem[10240];
    h16* Asr; h16* Asi; h16* Bsr; h16* Bsi;
    Asr = smem; Asi = smem + 2560; Bsr = smem + 5120; Bsi = smem + 7680;
    const int t = threadIdx.x, bk = blockIdx.z, kk = bk & 3;
    const int N0 = blockIdx.x * 64, D0 = blockIdx.y * 64;
    const int wave = t >> 6, lane = t & 63, quad = lane >> 4, l16 = lane & 15;
    const int wy = wave >> 1, wx = wave & 1;

    f4 zero = {0.f, 0.f, 0.f, 0.f};
    f4 P1[2][2], P2[2][2];
#pragma unroll
    for (int r = 0; r < 2; ++r)
#pragma unroll
        for (int c = 0; c < 2; ++c) { P1[r][c] = zero; P2[r][c] = zero; }

    for (int c0 = 0; c0 < Cd; c0 += 32) {
        {   // stage A: out fp32 -> fp16
            int comp = t >> 7, rem = t & 127, row = rem >> 1, ch = rem & 1;
            const float4* sp = (const float4*)((comp ? outi : outr) + (size_t)kk * 262144 + (size_t)(D0 + row) * 512 + c0 + ch * 16);
            h8 h0v, h1v;
#pragma unroll
            for (int w = 0; w < 4; ++w) {
                float4 v = sp[w];
                h16 a = (h16)v.x, b2 = (h16)v.y, c = (h16)v.z, d = (h16)v.w;
                if (w < 2) { h0v[w*4] = a; h0v[w*4+1] = b2; h0v[w*4+2] = c; h0v[w*4+3] = d; }
                else { h1v[(w-2)*4] = a; h1v[(w-2)*4+1] = b2; h1v[(w-2)*4+2] = c; h1v[(w-2)*4+3] = d; }
            }
            h16* dst = (comp ? Asi : Asr) + row * 40 + ch * 16;
            *(h8*)dst = h0v; *(h8*)(dst + 8) = h1v;
        }
        {   // stage B: ctx_t fp16 copy
            int comp = t >> 7, rem = t & 127, row = rem >> 1, ch = rem & 1;
            const h16* src = (comp ? cti : ctr) + (size_t)bk * 524288 + (size_t)(N0 + row) * 512 + c0 + ch * 16;
            h16* dst = (comp ? Bsi : Bsr) + row * 40 + ch * 16;
            const uint4* s4 = (const uint4*)src; uint4 v0 = s4[0], v1 = s4[1];
            uint4* d4 = (uint4*)dst; d4[0] = v0; d4[1] = v1;
        }
        __syncthreads();
        h8 br[2], bi[2];
#pragma unroll
        for (int cc = 0; cc < 2; ++cc) {
            int o = (wx * 32 + cc * 16 + l16) * 40 + quad * 8;
            br[cc] = *(const h8*)(Bsr + o); bi[cc] = *(const h8*)(Bsi + o);
        }
#pragma unroll
        for (int rr = 0; rr < 2; ++rr) {
            int o = (wy * 32 + rr * 16 + l16) * 40 + quad * 8;
            h8 ar = *(const h8*)(Asr + o), ai = *(const h8*)(Asi + o);
#pragma unroll
            for (int cc = 0; cc < 2; ++cc) {
                P1[rr][cc] = MFMA16(ar, br[cc], P1[rr][cc]);
                P2[rr][cc] = MFMA16(ai, bi[cc], P2[rr][cc]);
            }
        }
        __syncthreads();
    }
#pragma unroll
    for (int rr = 0; rr < 2; ++rr)
#pragma unroll
        for (int cc = 0; cc < 2; ++cc)
#pragma unroll
            for (int reg = 0; reg < 4; ++reg) {
                int dl = D0 + wy * 32 + rr * 16 + quad * 4 + reg;
                int nl = N0 + wx * 32 + cc * 16 + l16;
                res[(size_t)bk * 524288 + (size_t)dl * 1024 + nl] = P1[rr][cc][reg] - P2[rr][cc][reg];
            }
}

extern "C" void kernel_launch(void* const* d_in, const int* in_sizes, int n_in,
                              void* d_out, int out_size, void* d_ws, size_t ws_size,
                              hipStream_t stream)
{
    const float* xr    = (const float*)d_in[0];
    const float* xi    = (const float*)d_in[1];
    const float* embr  = (const float*)d_in[2];
    const float* embi  = (const float*)d_in[3];
    const float* encr  = (const float*)d_in[4];
    const float* enci  = (const float*)d_in[5];
    const float* softr = (const float*)d_in[6];
    const float* softi = (const float*)d_in[7];
    const float* outr  = (const float*)d_in[8];
    const float* outi  = (const float*)d_in[9];
    float* res = (float*)d_out;
    char* ws   = (char*)d_ws;
    if (ws_size < (size_t)268435456) return;

    h16* qhr = (h16*)(ws + QHR); h16* qlr = (h16*)(ws + QLR);
    h16* qhi = (h16*)(ws + QHI); h16* qli = (h16*)(ws + QLI);
    h16* khr = (h16*)(ws + KHR); h16* klr = (h16*)(ws + KLR);
    h16* khi = (h16*)(ws + KHI); h16* kli = (h16*)(ws + KLI);
    float* S  = (float*)(ws + SOFF);
    h16* xthr = (h16*)(ws + XTHR); h16* xtlr = (h16*)(ws + XTLR);
    h16* xthi = (h16*)(ws + XTHI); h16* xtli = (h16*)(ws + XTLI);
    h16* ehr = (h16*)(ws + EHR); h16* elr = (h16*)(ws + ELR);
    h16* ehi = (h16*)(ws + EHI); h16* eli = (h16*)(ws + ELI);
    h16* x2hr = (h16*)(ws + X2HR); h16* x2hi = (h16*)(ws + X2HI);
    h16* e2hr = (h16*)(ws + E2HR); h16* e2hi = (h16*)(ws + E2HI);
    h16* vr = (h16*)(ws + VRO); h16* vi = (h16*)(ws + VIO);
    h16* ctr = (h16*)(ws + CTR); h16* cti = (h16*)(ws + CTI);
    float* sc = (float*)d_out;  // scratch in d_out, overwritten by k_out last
    float* ggr = sc + GG_R; float* ggi = sc + GG_I;
    float* wtc = sc + WT_C; float* wts = sc + WT_S;
    float* cmax = sc + CMAX; float* csum = sc + CSUM;

    k_prep_x<0><<<dim3(16, 8, 16), 256, 0, stream>>>(xr, xi, xthr, xtlr, xthi, xtli);
    k_prep_emb<0><<<dim3(2048), 256, 0, stream>>>(embr, embi, 0, ehr, elr, ehi, eli);
    k_wtab<<<dim3(16), 256, 0, stream>>>(wtc, wts);
    k_qkv01<<<dim3(16, 4, 32), 256, 0, stream>>>(ehr, elr, ehi, eli, xthr, xtlr, xthi, xtli,
                                                 qhr, qlr, qhi, qli, khr, klr, khi, kli, softr, softi);
    k_gg<<<dim3(4, 128), 256, 0, stream>>>(qhr, qlr, qhi, qli, encr, enci, softr, softi, ggr, ggi);
    k_scores<<<dim3(16, 16, 32), 256, 0, stream>>>(khr, klr, khi, kli, qhr, qlr, qhi, qli,
                                                   ggr, ggi, wtc, wts, S);
    k_colred<<<dim3(32768), 256, 0, stream>>>(S, cmax, csum);
    k_prep_x<1><<<dim3(16, 8, 16), 256, 0, stream>>>(xr, xi, x2hr, x2hr, x2hi, x2hi);
    k_prep_emb<1><<<dim3(1024), 256, 0, stream>>>(embr, embi, 2097152, e2hr, e2hr, e2hi, e2hi);
    k_qkv_v<<<dim3(16, 4, 16), 256, 0, stream>>>(e2hr, e2hi, x2hr, x2hi, vr, vi);
    k_ctx<<<dim3(16, 4, 32), 256, 0, stream>>>(vr, vi, S, cmax, csum, ctr, cti);
    k_out<<<dim3(16, 8, 16), 256, 0, stream>>>(outr, outi, ctr, cti, res);
}